// Round 3
// baseline (164.228 us; speedup 1.0000x reference)
//
#include <hip/hip_runtime.h>
#include <hip/hip_bf16.h>
#include <stdint.h>

// Problem constants (fixed by setup_inputs)
#define M_N  16384   // batch rows
#define K_C  2048    // centers
#define DIM  512     // feature dim
#define NCLS 10      // classes
#define NBN  (K_C / 128)   // 16 center-blocks -> partial slices

typedef unsigned short u16;
typedef float  f32x4  __attribute__((ext_vector_type(4)));
typedef __bf16 bf16x8 __attribute__((ext_vector_type(8)));

// ---- helpers -------------------------------------------------------------

__device__ __forceinline__ void async_ld16(const void* g, void* l) {
  // global -> LDS direct DMA, 16 bytes per lane. LDS dest is wave-uniform
  // base + lane*16 (lds off linear in tid) -- swizzle must be on the SOURCE.
  __builtin_amdgcn_global_load_lds(
      (const __attribute__((address_space(1))) void*)g,
      (__attribute__((address_space(3))) void*)l,
      16, 0, 0);
}

__device__ __forceinline__ u16 f2bf_rne(float f) {
  uint32_t u = __float_as_uint(f);
  u += 0x7FFFu + ((u >> 16) & 1u);
  return (u16)(u >> 16);
}

// ---- kernel 1: fp32 [R][512] -> bf16 [R][512] + row sum-of-squares -------
// one row per wave, 4 rows per 256-thread block

__global__ __launch_bounds__(256) void convert_rows(
    const float4* __restrict__ src, ushort4* __restrict__ dst,
    float* __restrict__ sq, int nrows) {
  int lane = threadIdx.x & 63;
  int row = blockIdx.x * 4 + (threadIdx.x >> 6);
  if (row >= nrows) return;
  float ss = 0.f;
#pragma unroll
  for (int i = 0; i < 2; ++i) {
    float4 v = src[(size_t)row * 128 + lane * 2 + i];
    ss += v.x * v.x + v.y * v.y + v.z * v.z + v.w * v.w;
    ushort4 o;
    o.x = f2bf_rne(v.x); o.y = f2bf_rne(v.y);
    o.z = f2bf_rne(v.z); o.w = f2bf_rne(v.w);
    dst[(size_t)row * 128 + lane * 2 + i] = o;
  }
  ss += __shfl_down(ss, 32);
  ss += __shfl_down(ss, 16);
  ss += __shfl_down(ss, 8);
  ss += __shfl_down(ss, 4);
  ss += __shfl_down(ss, 2);
  ss += __shfl_down(ss, 1);
  if (lane == 0) sq[row] = ss;
}

// ---- kernel 2: fused  xc-GEMM -> radial -> partial (radial @ W^T) --------
// grid = (NBN, M_N/128), block = 256 (4 waves, 2x2 of 64x64). BK=64.
// LDS tiles XOR-swizzled: slot s of row r holds global chunk s^(r&7).

__global__ __launch_bounds__(256, 4) void rbf_main(
    const u16* __restrict__ A,      // bf16 bits [M_N][DIM]
    const u16* __restrict__ B,      // bf16 bits [K_C][DIM]
    const float* __restrict__ x2,   // [M_N]
    const float* __restrict__ c2,   // [K_C]
    const float* __restrict__ beta, // [K_C]
    const float* __restrict__ W,    // [NCLS][K_C]
    float* __restrict__ partial) {  // [NBN][M_N][NCLS]
  constexpr int BK = 64;
  constexpr int RLD = 128 + 4;  // radial LDS row stride (u16)
  __shared__ alignas(16) unsigned char smem[128 * RLD * 2];  // 33792 B
  u16* As = (u16*)smem;           // [128][64] swizzled
  u16* Bs = (u16*)(smem + 16384); // [128][64] swizzled
  u16* Rt = (u16*)smem;           // [128][RLD] transposed radial (bf16)

  const int tid  = threadIdx.x;
  const int lane = tid & 63;
  const int wid  = tid >> 6;
  const int bn = blockIdx.x, bm = blockIdx.y;
  const int row0 = bm * 128, col0 = bn * 128;
  const int wr = (wid >> 1) * 64;   // wave row offset in tile
  const int wc = (wid & 1) * 64;    // wave col offset in tile

  f32x4 acc[4][4] = {};

  // staging: thread t -> LDS slot (row=t>>3, s=t&7); loads global chunk
  // g = s ^ (row&7) so LDS[r][c^(r&7)] = global (r, chunk c).
  const int srow = tid >> 3;
  const int scol = ((tid & 7) ^ (srow & 7)) * 8;
  const u16* aG = A + (size_t)(row0 + srow) * DIM + scol;
  const u16* bG = B + (size_t)(col0 + srow) * DIM + scol;
  u16* aL = As + tid * 8;
  u16* bL = Bs + tid * 8;

  const int frow = lane & 15;      // MFMA A/B operand row (m or n)
  const int fq   = lane >> 4;      // k-quarter: chunk index = kh*4 + fq
  const int fsw  = frow & 7;       // swizzle key

  for (int k0 = 0; k0 < DIM; k0 += BK) {
    __syncthreads();  // previous iter's ds_reads done before overwrite
#pragma unroll
    for (int i = 0; i < 4; ++i) {
      async_ld16(aG + k0 + i * 32 * DIM, aL + i * 2048);
      async_ld16(bG + k0 + i * 32 * DIM, bL + i * 2048);
    }
    __syncthreads();  // vmcnt drained before s_barrier -> tiles ready

#pragma unroll
    for (int kh = 0; kh < 2; ++kh) {
      const int slot = ((kh << 2) | fq) ^ fsw;   // swizzled 16B chunk
      bf16x8 af[4], bfr[4];
#pragma unroll
      for (int mi = 0; mi < 4; ++mi)
        af[mi] = *(const bf16x8*)(As + (wr + mi * 16 + frow) * BK + slot * 8);
#pragma unroll
      for (int ni = 0; ni < 4; ++ni)
        bfr[ni] = *(const bf16x8*)(Bs + (wc + ni * 16 + frow) * BK + slot * 8);
#pragma unroll
      for (int mi = 0; mi < 4; ++mi)
#pragma unroll
        for (int ni = 0; ni < 4; ++ni)
          acc[mi][ni] = __builtin_amdgcn_mfma_f32_16x16x32_bf16(
              af[mi], bfr[ni], acc[mi][ni], 0, 0, 0);
    }
  }

  // ---- epilogue: radial = exp(-beta*sqrt(max(x2+c2-2xc,0))) ----
  // C/D layout (16x16x32): col = lane&15, row = (lane>>4)*4 + reg
  float c2v[4], btv[4];
#pragma unroll
  for (int ni = 0; ni < 4; ++ni) {
    int gc = col0 + wc + ni * 16 + (lane & 15);
    c2v[ni] = c2[gc];
    btv[ni] = beta[gc];
  }
  float x2v[4][4];
#pragma unroll
  for (int mi = 0; mi < 4; ++mi)
#pragma unroll
    for (int r = 0; r < 4; ++r)
      x2v[mi][r] = x2[row0 + wr + mi * 16 + (lane >> 4) * 4 + r];

  __syncthreads();  // K-loop LDS use finished; smem becomes Rt

  union Pack { u16 h[4]; uint2 v; };
#pragma unroll
  for (int mi = 0; mi < 4; ++mi) {
#pragma unroll
    for (int ni = 0; ni < 4; ++ni) {
      Pack pk;
#pragma unroll
      for (int r = 0; r < 4; ++r) {
        float xc = acc[mi][ni][r];
        float d2 = fmaxf(x2v[mi][r] + c2v[ni] - 2.0f * xc, 0.0f);
        float radial = __expf(-btv[ni] * sqrtf(d2));
        pk.h[r] = f2bf_rne(radial);
      }
      int ccol = wc + ni * 16 + (lane & 15);
      int rrow = wr + mi * 16 + (lane >> 4) * 4;  // 4 consecutive rows
      *(uint2*)(Rt + ccol * RLD + rrow) = pk.v;   // 8B store, 8B aligned
    }
  }
  __syncthreads();

  // ---- reduce this block's 128 centers -> partial[bn] (plain stores) ----
  // thread t: row r = t&127, class-half jh = t>>7 (5 classes each)
  const int r  = tid & 127;
  const int jh = tid >> 7;   // wave-uniform
  float2 a01 = {0.f, 0.f}, a23 = {0.f, 0.f};
  float a4 = 0.f;
  for (int c = 0; c < 128; ++c) {
    uint32_t bits = (uint32_t)Rt[c * RLD + r];
    float v = __uint_as_float(bits << 16);
    int gw = jh * 5 * K_C + col0 + c;   // wave-uniform -> scalar loads of W
    float w0 = W[gw], w1 = W[gw + K_C], w2 = W[gw + 2 * K_C],
          w3 = W[gw + 3 * K_C], w4 = W[gw + 4 * K_C];
    a01.x += v * w0; a01.y += v * w1;   // v_pk_fma_f32
    a23.x += v * w2; a23.y += v * w3;
    a4 += v * w4;
  }
  float* dst = partial + (size_t)bn * (M_N * NCLS)
             + (size_t)(row0 + r) * NCLS + jh * 5;
  dst[0] = a01.x; dst[1] = a01.y; dst[2] = a23.x; dst[3] = a23.y; dst[4] = a4;
}

// ---- kernel 3: out[i][j] = b[j] + sum_bn partial[bn][i][j] ---------------

__global__ void reduce_out(const float* __restrict__ partial,
                           const float* __restrict__ b,
                           float* __restrict__ out) {
  int idx = blockIdx.x * 256 + threadIdx.x;
  if (idx >= M_N * NCLS) return;
  float s = b[idx % NCLS];
#pragma unroll
  for (int bn = 0; bn < NBN; ++bn)
    s += partial[(size_t)bn * (M_N * NCLS) + idx];
  out[idx] = s;
}

// ---- launch --------------------------------------------------------------

extern "C" void kernel_launch(void* const* d_in, const int* in_sizes, int n_in,
                              void* d_out, int out_size, void* d_ws, size_t ws_size,
                              hipStream_t stream) {
  const float* batches = (const float*)d_in[0];  // [16384,512]
  const float* centers = (const float*)d_in[1];  // [2048,512]
  const float* beta    = (const float*)d_in[2];  // [1,2048]
  const float* W       = (const float*)d_in[3];  // [10,2048]
  const float* bias    = (const float*)d_in[4];  // [10]
  float* out = (float*)d_out;                    // [16384,10]

  char* ws = (char*)d_ws;
  u16*  Abf = (u16*)ws;                                       // 16 MiB
  u16*  Bbf = (u16*)(ws + (size_t)M_N * DIM * 2);             // 2 MiB
  float* x2 = (float*)(ws + (size_t)M_N * DIM * 2 + (size_t)K_C * DIM * 2);
  float* c2 = x2 + M_N;
  float* partial = c2 + K_C;                                  // 10.5 MiB

  convert_rows<<<dim3(M_N / 4), dim3(256), 0, stream>>>(
      (const float4*)batches, (ushort4*)Abf, x2, M_N);
  convert_rows<<<dim3(K_C / 4), dim3(256), 0, stream>>>(
      (const float4*)centers, (ushort4*)Bbf, c2, K_C);
  rbf_main<<<dim3(NBN, M_N / 128), dim3(256), 0, stream>>>(
      Abf, Bbf, x2, c2, beta, W, partial);
  reduce_out<<<dim3((M_N * NCLS + 255) / 256), dim3(256), 0, stream>>>(
      partial, bias, out);
}

// Round 4
// 147.751 us; speedup vs baseline: 1.1115x; 1.1115x over previous
//
#include <hip/hip_runtime.h>
#include <hip/hip_bf16.h>
#include <stdint.h>

// Problem constants (fixed by setup_inputs)
#define M_N  16384   // batch rows
#define K_C  2048    // centers
#define DIM  512     // feature dim
#define NCLS 10      // classes
#define NBN  (K_C / 128)   // 16 center-blocks -> partial slices

typedef unsigned short u16;
typedef float  f32x4  __attribute__((ext_vector_type(4)));
typedef __bf16 bf16x8 __attribute__((ext_vector_type(8)));

// ---- helpers -------------------------------------------------------------

__device__ __forceinline__ void async_ld16(const void* g, void* l) {
  // global -> LDS direct DMA, 16 bytes per lane. LDS dest is wave-uniform
  // base + lane*16 (lds off linear in tid) -- swizzle must be on the SOURCE.
  __builtin_amdgcn_global_load_lds(
      (const __attribute__((address_space(1))) void*)g,
      (__attribute__((address_space(3))) void*)l,
      16, 0, 0);
}

__device__ __forceinline__ u16 f2bf_rne(float f) {
  uint32_t u = __float_as_uint(f);
  u += 0x7FFFu + ((u >> 16) & 1u);
  return (u16)(u >> 16);
}

// ---- kernel 1: fp32 [R][512] -> bf16 [R][512] + row sum-of-squares -------
// R1 form: 128 threads = 1 row, fully coalesced float4.

__global__ void convert_rows(const float4* __restrict__ src,
                             ushort4* __restrict__ dst,
                             float* __restrict__ sq) {
  int row = blockIdx.x;
  int t = threadIdx.x;                       // 128 threads, 4 floats each
  float4 v = src[(size_t)row * 128 + t];
  float ss = v.x * v.x + v.y * v.y + v.z * v.z + v.w * v.w;
  ushort4 o;
  o.x = f2bf_rne(v.x); o.y = f2bf_rne(v.y);
  o.z = f2bf_rne(v.z); o.w = f2bf_rne(v.w);
  dst[(size_t)row * 128 + t] = o;
  ss += __shfl_down(ss, 32);
  ss += __shfl_down(ss, 16);
  ss += __shfl_down(ss, 8);
  ss += __shfl_down(ss, 4);
  ss += __shfl_down(ss, 2);
  ss += __shfl_down(ss, 1);
  __shared__ float part[2];
  if ((t & 63) == 0) part[t >> 6] = ss;
  __syncthreads();
  if (t == 0) sq[row] = part[0] + part[1];
}

// ---- kernel 1b: W [10][2048] fp32 -> bf16 [16][2048], rows 10..15 = 0 ----

__global__ void convert_w(const float* __restrict__ W, u16* __restrict__ Wbf) {
  int idx = blockIdx.x * 256 + threadIdx.x;   // 16*2048 = 32768
  int n = idx >> 11, k = idx & 2047;
  float v = (n < NCLS) ? W[n * K_C + k] : 0.0f;
  Wbf[idx] = f2bf_rne(v);
}

// ---- kernel 2: fused xc-GEMM -> radial -> MFMA (radial @ W^T) ------------
// grid = (NBN, M_N/128), block = 256 (4 waves, 2x2 of 64x64). BK=64.
// Stage-1 computes D[center][batch] so acc regs = 4 consecutive CENTERS at a
// fixed batch row -> b64 writes into ROW-major Rt[batch][center] (swizzled).
// Stage-2: out2[batch][class] = mfma(radialFrag, wFrag) with W bf16 [16][2048].

__global__ __launch_bounds__(256, 4) void rbf_main(
    const u16* __restrict__ A,      // bf16 bits [M_N][DIM]  (batches)
    const u16* __restrict__ B,      // bf16 bits [K_C][DIM]  (centers)
    const float* __restrict__ x2,   // [M_N]
    const float* __restrict__ c2,   // [K_C]
    const float* __restrict__ beta, // [K_C]
    const u16* __restrict__ Wbf,    // bf16 bits [16][K_C]
    float* __restrict__ partial) {  // [M_N][NBN][16]
  constexpr int BK = 64;
  __shared__ alignas(16) unsigned char smem[32768];
  u16* As = (u16*)smem;            // batches [128][64] swizzled
  u16* Bs = (u16*)(smem + 16384);  // centers [128][64] swizzled
  u16* Rt = (u16*)smem;            // radial row-major [128][128] swizzled

  const int tid  = threadIdx.x;
  const int lane = tid & 63;
  const int wid  = tid >> 6;
  const int bn = blockIdx.x, bm = blockIdx.y;
  const int row0 = bm * 128, col0 = bn * 128;
  const int wrC = (wid >> 1) * 64;   // wave CENTER offset in tile
  const int wcB = (wid & 1) * 64;    // wave BATCH offset in tile

  f32x4 acc[4][4] = {};   // acc[mi = center strip][ni = batch strip]

  // staging: thread t -> LDS slot (row=t>>3, s=t&7); loads global chunk
  // g = s ^ (row&7) so LDS[r][c^(r&7)] = global (r, chunk c).
  const int srow = tid >> 3;
  const int scol = ((tid & 7) ^ (srow & 7)) * 8;
  const u16* aG = A + (size_t)(row0 + srow) * DIM + scol;
  const u16* bG = B + (size_t)(col0 + srow) * DIM + scol;
  u16* aL = As + tid * 8;
  u16* bL = Bs + tid * 8;

  const int frow = lane & 15;      // MFMA operand row (m or n)
  const int fq   = lane >> 4;      // k-quarter
  const int fsw  = frow & 7;       // swizzle key

  for (int k0 = 0; k0 < DIM; k0 += BK) {
    __syncthreads();  // previous iter's ds_reads done before overwrite
#pragma unroll
    for (int i = 0; i < 4; ++i) {
      async_ld16(aG + k0 + i * 32 * DIM, aL + i * 2048);
      async_ld16(bG + k0 + i * 32 * DIM, bL + i * 2048);
    }
    __syncthreads();  // vmcnt drained before s_barrier -> tiles ready

#pragma unroll
    for (int kh = 0; kh < 2; ++kh) {
      const int slot = ((kh << 2) | fq) ^ fsw;   // swizzled 16B chunk
      bf16x8 cf[4], bfr[4];
#pragma unroll
      for (int mi = 0; mi < 4; ++mi)   // centers = FIRST operand
        cf[mi] = *(const bf16x8*)(Bs + (wrC + mi * 16 + frow) * BK + slot * 8);
#pragma unroll
      for (int ni = 0; ni < 4; ++ni)   // batches = SECOND operand
        bfr[ni] = *(const bf16x8*)(As + (wcB + ni * 16 + frow) * BK + slot * 8);
#pragma unroll
      for (int mi = 0; mi < 4; ++mi)
#pragma unroll
        for (int ni = 0; ni < 4; ++ni)
          acc[mi][ni] = __builtin_amdgcn_mfma_f32_16x16x32_bf16(
              cf[mi], bfr[ni], acc[mi][ni], 0, 0, 0);
    }
  }

  // ---- W fragments for stage 2 (global, L2-hot): issue early ----
  const int cls = lane & 15, q = lane >> 4;
  bf16x8 wfr[4];
#pragma unroll
  for (int t = 0; t < 4; ++t)
    wfr[t] = *(const bf16x8*)(Wbf + (size_t)cls * K_C + col0 + t * 32 + q * 8);

  // ---- epilogue scalars ----
  // D layout: col(lane&15)=batch within 16-strip, row(q*4+reg)=center.
  float4 c2q[4], btq[4];
#pragma unroll
  for (int mi = 0; mi < 4; ++mi) {
    int base = col0 + wrC + mi * 16 + q * 4;   // 4 consecutive centers
    c2q[mi] = *(const float4*)(c2 + base);
    btq[mi] = *(const float4*)(beta + base);
  }
  float x2v[4];
#pragma unroll
  for (int ni = 0; ni < 4; ++ni)
    x2v[ni] = x2[row0 + wcB + ni * 16 + cls];

  __syncthreads();  // K-loop LDS use finished; smem becomes Rt

  // Rt[br][cc] stored at br*128 + (cc ^ ((br&15)<<3))
  union Pack { u16 h[4]; uint2 v; };
#pragma unroll
  for (int mi = 0; mi < 4; ++mi) {
#pragma unroll
    for (int ni = 0; ni < 4; ++ni) {
      Pack pk;
#pragma unroll
      for (int r = 0; r < 4; ++r) {
        float xc = acc[mi][ni][r];
        float d2 = fmaxf(x2v[ni] + c2q[mi][r] - 2.0f * xc, 0.0f);
        float radial = __expf(-btq[mi][r] * sqrtf(d2));
        pk.h[r] = f2bf_rne(radial);
      }
      int br  = wcB + ni * 16 + cls;           // batch row in tile
      int cc0 = wrC + mi * 16 + q * 4;         // 4 consecutive centers
      *(uint2*)(Rt + br * 128 + (cc0 ^ ((br & 15) << 3))) = pk.v;
    }
  }
  __syncthreads();

  // ---- stage 2: out2[128 x 16] = radial[128 x 128] @ W^T via MFMA ----
  // 8 strips of 16 rows; 2 strips per wave; K=128 -> 4 MFMA per strip.
  f32x4 acc2[2] = {};
#pragma unroll
  for (int s2 = 0; s2 < 2; ++s2) {
    const int br = (wid * 2 + s2) * 16 + cls;
    const u16* rrow = Rt + br * 128;
    const int sw = cls << 3;                   // (br&15)<<3 == cls<<3
#pragma unroll
    for (int t = 0; t < 4; ++t) {
      bf16x8 ra = *(const bf16x8*)(rrow + ((t * 32 + q * 8) ^ sw));
      acc2[s2] = __builtin_amdgcn_mfma_f32_16x16x32_bf16(
          ra, wfr[t], acc2[s2], 0, 0, 0);
    }
  }

  // store: D2 col(lane&15)=class, row(q*4+r)=batch row within strip.
  // cols 10..15 are exact zeros (W rows zeroed); reduce_out ignores them.
#pragma unroll
  for (int s2 = 0; s2 < 2; ++s2)
#pragma unroll
    for (int r = 0; r < 4; ++r) {
      int gr = row0 + (wid * 2 + s2) * 16 + q * 4 + r;
      partial[(size_t)gr * (NBN * 16) + bn * 16 + cls] = acc2[s2][r];
    }
}

// ---- kernel 3: out[i][j] = b[j] + sum_bn partial[i][bn][j] ---------------

__global__ void reduce_out(const float* __restrict__ partial,
                           const float* __restrict__ b,
                           float* __restrict__ out) {
  int idx = blockIdx.x * 256 + threadIdx.x;
  if (idx >= M_N * NCLS) return;
  int i = idx / NCLS, j = idx - i * NCLS;
  float s = b[j];
  const float* p = partial + (size_t)i * (NBN * 16) + j;
#pragma unroll
  for (int bn = 0; bn < NBN; ++bn) s += p[bn * 16];
  out[idx] = s;
}

// ---- launch --------------------------------------------------------------

extern "C" void kernel_launch(void* const* d_in, const int* in_sizes, int n_in,
                              void* d_out, int out_size, void* d_ws, size_t ws_size,
                              hipStream_t stream) {
  const float* batches = (const float*)d_in[0];  // [16384,512]
  const float* centers = (const float*)d_in[1];  // [2048,512]
  const float* beta    = (const float*)d_in[2];  // [1,2048]
  const float* W       = (const float*)d_in[3];  // [10,2048]
  const float* bias    = (const float*)d_in[4];  // [10]
  float* out = (float*)d_out;                    // [16384,10]

  char* ws = (char*)d_ws;
  u16*  Abf = (u16*)ws;                                   // 16 MiB
  u16*  Bbf = (u16*)(ws + (size_t)M_N * DIM * 2);         // 2 MiB
  float* x2 = (float*)(ws + (size_t)(M_N + K_C) * DIM * 2);
  float* c2 = x2 + M_N;
  u16*  Wbf = (u16*)(c2 + K_C);                           // 64 KiB
  float* partial = (float*)((char*)Wbf + 16 * K_C * 2);   // 16.8 MiB

  convert_rows<<<dim3(M_N), dim3(128), 0, stream>>>(
      (const float4*)batches, (ushort4*)Abf, x2);
  convert_rows<<<dim3(K_C), dim3(128), 0, stream>>>(
      (const float4*)centers, (ushort4*)Bbf, c2);
  convert_w<<<dim3(16 * K_C / 256), dim3(256), 0, stream>>>(W, Wbf);
  rbf_main<<<dim3(NBN, M_N / 128), dim3(256), 0, stream>>>(
      Abf, Bbf, x2, c2, beta, Wbf, partial);
  reduce_out<<<dim3((M_N * NCLS + 255) / 256), dim3(256), 0, stream>>>(
      partial, bias, out);
}